// Round 1
// baseline (1233.029 us; speedup 1.0000x reference)
//
#include <hip/hip_runtime.h>

// Problem constants (from reference)
constexpr int Bn    = 32;
constexpr int Sn    = 2048;
constexpr int Fn    = 128;
constexpr int DKn   = 32;    // d_k == d_v
constexpr int NHn   = 16;
constexpr int FILTn = 3;
constexpr int Mn    = Bn * Sn;  // 65536 rows

// ---------------------------------------------------------------------------
// Kernel A: fused QKV projection.
//   q = q_in @ Wq + bq ; k = k_in @ Wk + bk ; v = v_in @ Wv + bv
// Block = 256 threads = (8 rows x 32 cols) per iter, 8 iters -> 64 rows/block.
// Weights staged in LDS (48 KB); W read address has bank == col -> conflict-free
// (2 lanes per bank share the address -> broadcast, free per m136).
// ---------------------------------------------------------------------------
__global__ __launch_bounds__(256) void qkv_proj_kernel(
    const float* __restrict__ q_in, const float* __restrict__ k_in,
    const float* __restrict__ v_in,
    const float* __restrict__ Wq, const float* __restrict__ bq,
    const float* __restrict__ Wk, const float* __restrict__ bk,
    const float* __restrict__ Wv, const float* __restrict__ bv,
    float* __restrict__ q_ws, float* __restrict__ k_ws,
    float* __restrict__ v_ws)
{
    __shared__ float Wsh[3 * Fn * DKn];   // 48 KB
    __shared__ float bsh[3 * DKn];

    const int t = threadIdx.x;
    {
        float4*       dst = (float4*)Wsh;
        const float4* s0  = (const float4*)Wq;
        const float4* s1  = (const float4*)Wk;
        const float4* s2  = (const float4*)Wv;
        constexpr int n4 = Fn * DKn / 4;  // 1024
        for (int i = t; i < n4; i += 256) {
            dst[i]          = s0[i];
            dst[i + n4]     = s1[i];
            dst[i + 2 * n4] = s2[i];
        }
        if (t < DKn) {
            bsh[t]           = bq[t];
            bsh[DKn + t]     = bk[t];
            bsh[2 * DKn + t] = bv[t];
        }
    }
    __syncthreads();

    const int c    = t & 31;
    const int rg   = t >> 5;
    const int row0 = blockIdx.x * 64;
    const float* wq = Wsh;
    const float* wk = Wsh + Fn * DKn;
    const float* wv = Wsh + 2 * Fn * DKn;

    for (int it = 0; it < 8; ++it) {
        const int row = row0 + it * 8 + rg;
        const float4* iq = (const float4*)(q_in + (size_t)row * Fn);
        const float4* ik = (const float4*)(k_in + (size_t)row * Fn);
        const float4* iv = (const float4*)(v_in + (size_t)row * Fn);
        float aq = bsh[c];
        float ak = bsh[DKn + c];
        float av = bsh[2 * DKn + c];
#pragma unroll 8
        for (int k4 = 0; k4 < Fn / 4; ++k4) {
            const float4 xq = iq[k4];
            const float4 xk = ik[k4];
            const float4 xv = iv[k4];
            const int kb = k4 * 4;
            aq += xq.x * wq[(kb + 0) * DKn + c];
            aq += xq.y * wq[(kb + 1) * DKn + c];
            aq += xq.z * wq[(kb + 2) * DKn + c];
            aq += xq.w * wq[(kb + 3) * DKn + c];
            ak += xk.x * wk[(kb + 0) * DKn + c];
            ak += xk.y * wk[(kb + 1) * DKn + c];
            ak += xk.z * wk[(kb + 2) * DKn + c];
            ak += xk.w * wk[(kb + 3) * DKn + c];
            av += xv.x * wv[(kb + 0) * DKn + c];
            av += xv.y * wv[(kb + 1) * DKn + c];
            av += xv.z * wv[(kb + 2) * DKn + c];
            av += xv.w * wv[(kb + 3) * DKn + c];
        }
        q_ws[(size_t)row * DKn + c] = aq;
        k_ws[(size_t)row * DKn + c] = ak;
        v_ws[(size_t)row * DKn + c] = av;
    }
}

// ---------------------------------------------------------------------------
// Kernel B: flash attention + fused output projection.
// 1 wave (64 threads) per block; lane = one query row; 64 queries/block.
// Grid = 32 batches x 32 q-tiles = 1024 blocks.
// K/V tiles of 64 keys staged in LDS; per-lane reads are all-lane broadcasts.
// Online softmax in exp2 domain: scale = (1/sqrt(32)) * log2(e) folded into q.
// Epilogue: out = (o/l) @ Wo_eff + bo, Wo_eff = sum of the 16 head blocks of Wo.
// ---------------------------------------------------------------------------
__global__ __launch_bounds__(64) void flash_attn_kernel(
    const float* __restrict__ q_ws, const float* __restrict__ k_ws,
    const float* __restrict__ v_ws,
    const float* __restrict__ Wo, const float* __restrict__ bo,
    float* __restrict__ out)
{
    __shared__ float ksh[64 * DKn];        // 8 KB
    __shared__ float vsh[64 * DKn];        // 8 KB
    __shared__ float wosh[DKn * FILTn];    // Wo_eff, 96 floats
    __shared__ float bosh[FILTn];

    const int t  = threadIdx.x;            // 0..63
    const int b  = blockIdx.x >> 5;        // batch (32 tiles per batch)
    const int qt = blockIdx.x & 31;

    // Wo_eff[d][f] = sum_h Wo[h*32 + d][f]
    for (int idx = t; idx < DKn * FILTn; idx += 64) {
        const int d = idx / FILTn;
        const int f = idx - d * FILTn;
        float s = 0.f;
#pragma unroll
        for (int h = 0; h < NHn; ++h) s += Wo[(h * DKn + d) * FILTn + f];
        wosh[idx] = s;
    }
    if (t < FILTn) bosh[t] = bo[t];

    const int qrow = b * Sn + qt * 64 + t;
    // softmax scale folded with log2(e) so we can use exp2 (v_exp_f32)
    const float scale = 0.1767766952966369f * 1.4426950408889634f;

    float q[DKn];
    {
        const float4* qp = (const float4*)(q_ws + (size_t)qrow * DKn);
#pragma unroll
        for (int i = 0; i < DKn / 4; ++i) {
            const float4 x = qp[i];
            q[4 * i + 0] = x.x * scale;
            q[4 * i + 1] = x.y * scale;
            q[4 * i + 2] = x.z * scale;
            q[4 * i + 3] = x.w * scale;
        }
    }
    float o[DKn];
#pragma unroll
    for (int d = 0; d < DKn; ++d) o[d] = 0.f;
    float m = -1e30f;
    float l = 0.f;

    const float* Kb = k_ws + (size_t)b * Sn * DKn;
    const float* Vb = v_ws + (size_t)b * Sn * DKn;

    for (int kt = 0; kt < Sn / 64; ++kt) {
        // Cooperative tile load: 512 float4 per tensor, 8 per thread.
        const float4* ks4 = (const float4*)(Kb + (size_t)kt * 64 * DKn);
        const float4* vs4 = (const float4*)(Vb + (size_t)kt * 64 * DKn);
        float4* kd = (float4*)ksh;
        float4* vd = (float4*)vsh;
#pragma unroll
        for (int i = 0; i < 8; ++i) {
            kd[t + 64 * i] = ks4[t + 64 * i];
            vd[t + 64 * i] = vs4[t + 64 * i];
        }
        __syncthreads();

#pragma unroll 1
        for (int j0 = 0; j0 < 64; j0 += 16) {
            float s[16];
#pragma unroll
            for (int jj = 0; jj < 16; ++jj) {
                const float4* kr = (const float4*)(ksh + (j0 + jj) * DKn);
                float acc = 0.f;
#pragma unroll
                for (int i = 0; i < 8; ++i) {
                    const float4 x = kr[i];
                    acc += q[4 * i + 0] * x.x;
                    acc += q[4 * i + 1] * x.y;
                    acc += q[4 * i + 2] * x.z;
                    acc += q[4 * i + 3] * x.w;
                }
                s[jj] = acc;
            }
            float cmax = s[0];
#pragma unroll
            for (int jj = 1; jj < 16; ++jj) cmax = fmaxf(cmax, s[jj]);
            const float mnew  = fmaxf(m, cmax);
            const float alpha = __builtin_amdgcn_exp2f(m - mnew);
            m = mnew;
            l *= alpha;
#pragma unroll
            for (int d = 0; d < DKn; ++d) o[d] *= alpha;
#pragma unroll
            for (int jj = 0; jj < 16; ++jj) {
                const float p = __builtin_amdgcn_exp2f(s[jj] - mnew);
                l += p;
                const float4* vr = (const float4*)(vsh + (j0 + jj) * DKn);
#pragma unroll
                for (int i = 0; i < 8; ++i) {
                    const float4 x = vr[i];
                    o[4 * i + 0] += p * x.x;
                    o[4 * i + 1] += p * x.y;
                    o[4 * i + 2] += p * x.z;
                    o[4 * i + 3] += p * x.w;
                }
            }
        }
        __syncthreads();
    }

    // Epilogue: out[qrow][f] = sum_d (o[d]/l) * Wo_eff[d][f] + bo[f]
    const float inv = 1.f / l;
    float r[FILTn];
#pragma unroll
    for (int f = 0; f < FILTn; ++f) r[f] = bosh[f];
#pragma unroll
    for (int d = 0; d < DKn; ++d) {
        const float od = o[d] * inv;
#pragma unroll
        for (int f = 0; f < FILTn; ++f) r[f] += od * wosh[d * FILTn + f];
    }
#pragma unroll
    for (int f = 0; f < FILTn; ++f) out[(size_t)qrow * FILTn + f] = r[f];
}

// ---------------------------------------------------------------------------
// Launch. Workspace layout (fp32): q_ws | k_ws | v_ws, each Mn*DKn floats
// = 3 * 8 MiB = 25.2 MB total.
// ---------------------------------------------------------------------------
extern "C" void kernel_launch(void* const* d_in, const int* in_sizes, int n_in,
                              void* d_out, int out_size, void* d_ws,
                              size_t ws_size, hipStream_t stream)
{
    const float* q_in = (const float*)d_in[0];
    const float* k_in = (const float*)d_in[1];
    const float* v_in = (const float*)d_in[2];
    const float* Wq   = (const float*)d_in[3];
    const float* bq   = (const float*)d_in[4];
    const float* Wk   = (const float*)d_in[5];
    const float* bk   = (const float*)d_in[6];
    const float* Wv   = (const float*)d_in[7];
    const float* bv   = (const float*)d_in[8];
    const float* Wo   = (const float*)d_in[9];
    const float* bo   = (const float*)d_in[10];
    float* out = (float*)d_out;

    float* ws   = (float*)d_ws;
    float* q_ws = ws;
    float* k_ws = ws + (size_t)Mn * DKn;
    float* v_ws = ws + 2 * (size_t)Mn * DKn;

    qkv_proj_kernel<<<Mn / 64, 256, 0, stream>>>(
        q_in, k_in, v_in, Wq, bq, Wk, bk, Wv, bv, q_ws, k_ws, v_ws);

    flash_attn_kernel<<<Bn * (Sn / 64), 64, 0, stream>>>(
        q_ws, k_ws, v_ws, Wo, bo, out);
}

// Round 2
// 222.869 us; speedup vs baseline: 5.5325x; 5.5325x over previous
//
#include <hip/hip_runtime.h>

using f16 = _Float16;
typedef _Float16 f16x8 __attribute__((ext_vector_type(8)));
typedef float f32x4 __attribute__((ext_vector_type(4)));

constexpr int Bn    = 32;
constexpr int Sn    = 2048;
constexpr int Fn    = 128;
constexpr int DKn   = 32;
constexpr int NHn   = 16;
constexpr int FILTn = 3;
constexpr int Mn    = Bn * Sn;

// softmax scale (1/sqrt(32)) * log2(e), folded into Wq/bq at projection time
constexpr float QSCALE = 0.1767766952966369f * 1.4426950408889634f;

// LDS strides chosen for bank-uniform b128 access (see analysis):
constexpr int KSTR = 40;  // f16 per K-tile row   (64 rows)  -> 5120 B
constexpr int VSTR = 72;  // f16 per Vt row       (32 rows)  -> 4608 B
constexpr int PSTR = 68;  // f32 words per P row  (16 rows x 4 waves) -> 17408 B

// ---------------------------------------------------------------------------
// Kernel A: QKV projection via MFMA f16. Each wave = one 16-row M-tile,
// K=128 (4 ksteps), N=32 (2 n-tiles), for each of the 3 tensors.
// Outputs f16: q_ws [row][d] (pre-scaled), k_ws [b][s][d], v_ws [b][d][s].
// ---------------------------------------------------------------------------
__global__ __launch_bounds__(256) void qkv_proj_mfma(
    const float* __restrict__ q_in, const float* __restrict__ k_in,
    const float* __restrict__ v_in,
    const float* __restrict__ Wq, const float* __restrict__ bq,
    const float* __restrict__ Wk, const float* __restrict__ bk,
    const float* __restrict__ Wv, const float* __restrict__ bv,
    f16* __restrict__ q_ws, f16* __restrict__ k_ws, f16* __restrict__ v_ws)
{
    const int t    = threadIdx.x;
    const int w    = t >> 6;
    const int lane = t & 63;
    const int n    = lane & 15;
    const int quad = lane >> 4;
    const int row0 = (blockIdx.x * 4 + w) * 16;

    const float* ins[3] = {q_in, k_in, v_in};
    const float* Ws[3]  = {Wq, Wk, Wv};
    const float* bs[3]  = {bq, bk, bv};

    for (int T = 0; T < 3; ++T) {
        const float sc = (T == 0) ? QSCALE : 1.0f;
        // B fragments: B[k=quad*8+j][nn = nt*16+n] = W[k][nn], scaled for q.
        f16x8 bf[4][2];
        for (int ks = 0; ks < 4; ++ks)
            for (int nt = 0; nt < 2; ++nt) {
#pragma unroll
                for (int j = 0; j < 8; ++j)
                    bf[ks][nt][j] =
                        (f16)(Ws[T][(ks * 32 + quad * 8 + j) * DKn + nt * 16 + n] * sc);
            }
        const float b0 = bs[T][n] * sc;
        const float b1 = bs[T][16 + n] * sc;
        f32x4 acc0 = {b0, b0, b0, b0};
        f32x4 acc1 = {b1, b1, b1, b1};

#pragma unroll
        for (int ks = 0; ks < 4; ++ks) {
            const float* src = ins[T] + (size_t)(row0 + n) * Fn + ks * 32 + quad * 8;
            const float4 x0 = *(const float4*)(src);
            const float4 x1 = *(const float4*)(src + 4);
            f16x8 a;
            a[0] = (f16)x0.x; a[1] = (f16)x0.y; a[2] = (f16)x0.z; a[3] = (f16)x0.w;
            a[4] = (f16)x1.x; a[5] = (f16)x1.y; a[6] = (f16)x1.z; a[7] = (f16)x1.w;
            acc0 = __builtin_amdgcn_mfma_f32_16x16x32_f16(a, bf[ks][0], acc0, 0, 0, 0);
            acc1 = __builtin_amdgcn_mfma_f32_16x16x32_f16(a, bf[ks][1], acc1, 0, 0, 0);
        }

        if (T == 0) {
#pragma unroll
            for (int r = 0; r < 4; ++r) {
                const int row = row0 + quad * 4 + r;
                q_ws[(size_t)row * DKn + n]      = (f16)acc0[r];
                q_ws[(size_t)row * DKn + 16 + n] = (f16)acc1[r];
            }
        } else if (T == 1) {
#pragma unroll
            for (int r = 0; r < 4; ++r) {
                const int row = row0 + quad * 4 + r;
                k_ws[(size_t)row * DKn + n]      = (f16)acc0[r];
                k_ws[(size_t)row * DKn + 16 + n] = (f16)acc1[r];
            }
        } else {
#pragma unroll
            for (int r = 0; r < 4; ++r) {
                const int row = row0 + quad * 4 + r;
                const int b = row >> 11;       // / Sn
                const int s = row & (Sn - 1);
                v_ws[((size_t)(b * DKn + n)) * Sn + s]      = (f16)acc0[r];
                v_ws[((size_t)(b * DKn + 16 + n)) * Sn + s] = (f16)acc1[r];
            }
        }
    }
}

// ---------------------------------------------------------------------------
// Kernel B: MFMA flash attention + fused output projection.
// Block = 256 threads (4 waves). Block q-tile = 64 queries; wave = 16 queries.
// KV loop: 64-key tiles staged in LDS (K row-major padded, V transposed padded).
// P (scores->probs) round-trips through per-wave LDS to go C-layout -> A-layout.
// ---------------------------------------------------------------------------
__global__ __launch_bounds__(256) void flash_mfma(
    const f16* __restrict__ q_ws, const f16* __restrict__ k_ws,
    const f16* __restrict__ v_ws,
    const float* __restrict__ Wo, const float* __restrict__ bo,
    float* __restrict__ out)
{
    __shared__ f16   ksh[64 * KSTR];
    __shared__ f16   vsh[DKn * VSTR];
    __shared__ float psh[4 * 16 * PSTR];
    __shared__ float wosh[DKn * FILTn + FILTn];

    const int t    = threadIdx.x;
    const int w    = t >> 6;
    const int lane = t & 63;
    const int n    = lane & 15;
    const int quad = lane >> 4;
    const int b    = blockIdx.x >> 5;
    const int qt   = blockIdx.x & 31;

    // Wo_eff[d][f] = sum_h Wo[h*32+d][f]; bo appended.
    for (int idx = t; idx < DKn * FILTn; idx += 256) {
        const int d = idx / FILTn;
        const int f = idx - d * FILTn;
        float s = 0.f;
#pragma unroll
        for (int h = 0; h < NHn; ++h) s += Wo[(h * DKn + d) * FILTn + f];
        wosh[idx] = s;
    }
    if (t < FILTn) wosh[DKn * FILTn + t] = bo[t];

    // Q A-fragment (persistent): A[m=n][k=quad*8+j], q pre-scaled.
    const int qrow0 = b * Sn + qt * 64 + w * 16;
    const f16x8 qa = *(const f16x8*)(q_ws + (size_t)(qrow0 + n) * DKn + quad * 8);

    f32x4 o0 = {0.f, 0.f, 0.f, 0.f};
    f32x4 o1 = {0.f, 0.f, 0.f, 0.f};
    float m[4] = {-1e30f, -1e30f, -1e30f, -1e30f};
    float l[4] = {0.f, 0.f, 0.f, 0.f};

    const f16* Kb = k_ws + (size_t)b * Sn * DKn;
    const f16* Vb = v_ws + (size_t)b * DKn * Sn;
    float* pw = psh + w * 16 * PSTR;

    __syncthreads();

    for (int kt = 0; kt < Sn / 64; ++kt) {
        // --- stage K tile (row-major, stride KSTR) and Vt tile (stride VSTR)
        {
            const int krow = t >> 2, kpart = t & 3;
            const f16x8 kv =
                *(const f16x8*)(Kb + (size_t)(kt * 64 + krow) * DKn + kpart * 8);
            *(f16x8*)(ksh + krow * KSTR + kpart * 8) = kv;

            const int vd = t >> 3, vpart = t & 7;
            const f16x8 vv =
                *(const f16x8*)(Vb + (size_t)vd * Sn + kt * 64 + vpart * 8);
            *(f16x8*)(vsh + vd * VSTR + vpart * 8) = vv;
        }
        __syncthreads();

        // --- QK^T: 4 keygroups of 16 -> score frags (C-layout)
        f32x4 s[4];
#pragma unroll
        for (int g = 0; g < 4; ++g) {
            const f16x8 kb = *(const f16x8*)(ksh + (g * 16 + n) * KSTR + quad * 8);
            const f32x4 z = {0.f, 0.f, 0.f, 0.f};
            s[g] = __builtin_amdgcn_mfma_f32_16x16x32_f16(qa, kb, z, 0, 0, 0);
        }

        // --- online softmax (scores already in log2 domain)
#pragma unroll
        for (int r = 0; r < 4; ++r) {
            float v = fmaxf(fmaxf(s[0][r], s[1][r]), fmaxf(s[2][r], s[3][r]));
            v = fmaxf(v, __shfl_xor(v, 1, 16));
            v = fmaxf(v, __shfl_xor(v, 2, 16));
            v = fmaxf(v, __shfl_xor(v, 4, 16));
            v = fmaxf(v, __shfl_xor(v, 8, 16));
            const float mn = fmaxf(m[r], v);
            const float al = __builtin_amdgcn_exp2f(m[r] - mn);
            m[r] = mn;
            float psum = 0.f;
#pragma unroll
            for (int g = 0; g < 4; ++g) {
                const float p = __builtin_amdgcn_exp2f(s[g][r] - mn);
                psum += p;
                pw[(quad * 4 + r) * PSTR + g * 16 + n] = p;
            }
            l[r] = l[r] * al + psum;
            o0[r] *= al;
            o1[r] *= al;
        }

        // --- PV: P (A-layout via LDS) x Vt (B-layout, contiguous reads)
#pragma unroll
        for (int ks = 0; ks < 2; ++ks) {
            const float* pr = pw + n * PSTR + ks * 32 + quad * 8;
            const f32x4 p0 = *(const f32x4*)(pr);
            const f32x4 p1 = *(const f32x4*)(pr + 4);
            f16x8 pa;
#pragma unroll
            for (int j = 0; j < 4; ++j) {
                pa[j]     = (f16)p0[j];
                pa[4 + j] = (f16)p1[j];
            }
            const f16x8 vb0 =
                *(const f16x8*)(vsh + n * VSTR + ks * 32 + quad * 8);
            const f16x8 vb1 =
                *(const f16x8*)(vsh + (16 + n) * VSTR + ks * 32 + quad * 8);
            o0 = __builtin_amdgcn_mfma_f32_16x16x32_f16(pa, vb0, o0, 0, 0, 0);
            o1 = __builtin_amdgcn_mfma_f32_16x16x32_f16(pa, vb1, o1, 0, 0, 0);
        }
        __syncthreads();
    }

    // --- l reduction across the 16-lane group
#pragma unroll
    for (int r = 0; r < 4; ++r) {
        float v = l[r];
        v += __shfl_xor(v, 1, 16);
        v += __shfl_xor(v, 2, 16);
        v += __shfl_xor(v, 4, 16);
        v += __shfl_xor(v, 8, 16);
        l[r] = v;
    }

    // --- epilogue: out[row][f] = sum_d (O[row][d]/l) * Wo_eff[d][f] + bo[f]
#pragma unroll
    for (int r = 0; r < 4; ++r) {
        const float inv = 1.f / l[r];
        const float a0 = o0[r] * inv;
        const float a1 = o1[r] * inv;
#pragma unroll
        for (int f = 0; f < FILTn; ++f) {
            float v = a0 * wosh[n * FILTn + f] + a1 * wosh[(16 + n) * FILTn + f];
            v += __shfl_xor(v, 1, 16);
            v += __shfl_xor(v, 2, 16);
            v += __shfl_xor(v, 4, 16);
            v += __shfl_xor(v, 8, 16);
            if (n == f) {
                const int row = qrow0 + quad * 4 + r;
                out[(size_t)row * FILTn + f] = v + wosh[DKn * FILTn + f];
            }
        }
    }
}

// ---------------------------------------------------------------------------
// Launch. Workspace (f16): q_ws | k_ws | v_ws, each Mn*DKn = 4 MiB -> 12 MiB.
// ---------------------------------------------------------------------------
extern "C" void kernel_launch(void* const* d_in, const int* in_sizes, int n_in,
                              void* d_out, int out_size, void* d_ws,
                              size_t ws_size, hipStream_t stream)
{
    const float* q_in = (const float*)d_in[0];
    const float* k_in = (const float*)d_in[1];
    const float* v_in = (const float*)d_in[2];
    const float* Wq   = (const float*)d_in[3];
    const float* bq   = (const float*)d_in[4];
    const float* Wk   = (const float*)d_in[5];
    const float* bk   = (const float*)d_in[6];
    const float* Wv   = (const float*)d_in[7];
    const float* bv   = (const float*)d_in[8];
    const float* Wo   = (const float*)d_in[9];
    const float* bo   = (const float*)d_in[10];
    float* out = (float*)d_out;

    f16* ws   = (f16*)d_ws;
    f16* q_ws = ws;
    f16* k_ws = ws + (size_t)Mn * DKn;
    f16* v_ws = ws + 2 * (size_t)Mn * DKn;

    qkv_proj_mfma<<<Mn / 64, 256, 0, stream>>>(
        q_in, k_in, v_in, Wq, bq, Wk, bk, Wv, bv, q_ws, k_ws, v_ws);

    flash_mfma<<<Bn * (Sn / 64), 256, 0, stream>>>(
        q_ws, k_ws, v_ws, Wo, bo, out);
}